// Round 3
// baseline (286.686 us; speedup 1.0000x reference)
//
#include <hip/hip_runtime.h>
#include <stdint.h>

// DCN v1 forward: B=8, C=256, H=W=64, K=3, pad=1, stride=1, O=256.
// Round 6 (resubmit; R2 bench was an infra failure, no data): revert
// split-K/atomics (R5 regression: atomic RMW + memset + doubled fixed costs;
// occupancy never rose). Structural change vs the 147.5us baseline:
// 2-step-deep gather pipeline. Gathers for pair pr+2 are issued at step pr,
// consumed by reduce_store(pr+1) one full step later -> ~1 step (600-1000cy)
// of latency cover for the L2-thrashing gather stream (FETCH 15GB @207GB/s
// showed gathers run at HBM latency; old schedule covered them only with
// the ~200cy MFMA window). Two register chains (gA/tioA/twA, gB/tioB/twB);
// tap regs reload per-chain when (p&2)==0. +~24 VGPR, no LDS/traffic change.

#define Bb 8
#define Cc 256
#define Hh 64
#define Ww 64
#define Pp 4096
#define Oo 256
#define NK2 9
#define NPAIR 36             // 36 pairs of K-steps (BK=64 each)
#define BN 64
#define SROW 40              // padded S row stride (elems)
#define WT_BYTES (2u * 72u * 256u * 32u)  // 1,179,648

typedef __attribute__((ext_vector_type(4))) float f32x4;
typedef __attribute__((ext_vector_type(8))) short s16x8;
typedef __attribute__((ext_vector_type(4))) int   i32x4;

static __device__ __forceinline__ unsigned short f2bf(float f) {
    union { float f; uint32_t u; } v; v.f = f;
    return (unsigned short)((v.u + 0x7fffu + ((v.u >> 16) & 1u)) >> 16);  // RNE
}
static __device__ __forceinline__ int imin(int a, int b) { return a < b ? a : b; }
static __device__ __forceinline__ int imax(int a, int b) { return a > b ? a : b; }

// ---------------- fused prep: x-transpose (blocks 0..2047) + weight (2048..2111)
// xT[b][p][c] bf16 ; wt[ks(72)][oc(256)][c32(32)] bf16, ks = k2*8+cch.
__global__ __launch_bounds__(256)
void prep(const float* __restrict__ x, const float* __restrict__ w,
          unsigned short* __restrict__ xt, unsigned short* __restrict__ wt) {
    __shared__ __align__(16) unsigned short L[9216];   // 18 KB, dual-purpose
    const int bx = blockIdx.x, tid = threadIdx.x;

    if (bx < 2048) {
        // ---- x: tile 64 c x 64 px ; b = bx&7 keeps XCD affinity with dcn_main
        unsigned short (*t2)[72] = (unsigned short(*)[72])L;  // 64 x 72 shorts
        const int b = bx & 7, ti = bx >> 3;
        const int c0 = (ti & 3) * 64, p0 = (ti >> 2) * 64;
        #pragma unroll
        for (int rd = 0; rd < 4; rd++) {
            int c = (tid >> 4) + rd * 16;
            int px4 = (tid & 15) * 4;
            f32x4 fv = *(const f32x4*)&x[(size_t)(b * Cc + c0 + c) * Pp + p0 + px4];
            #pragma unroll
            for (int j = 0; j < 4; j++) {
                int px = px4 + j;
                int chunk = ((c >> 3) + px) & 7;      // rotate chunks to spread banks
                t2[px][chunk * 8 + (c & 7)] = f2bf(fv[j]);
            }
        }
        __syncthreads();
        #pragma unroll
        for (int rd = 0; rd < 2; rd++) {
            int px = (tid >> 3) + rd * 32;
            int k = tid & 7;
            int chunk = (k + px) & 7;
            uint4 u = *(const uint4*)&t2[px][chunk * 8];
            *(uint4*)&xt[(size_t)(b * Pp + p0 + px) * Cc + c0 + k * 8] = u;
        }
    } else {
        // ---- weight: 64 blocks x 4 o-rows
        const int o0 = (bx - 2048) * 4;
        #pragma unroll
        for (int r9 = 0; r9 < 9; r9++) {
            int idx = r9 * 256 + tid;                  // 0..2303 float4s over 4 rows
            f32x4 fv = *(const f32x4*)&w[(size_t)o0 * 2304 + (size_t)idx * 4];
            #pragma unroll
            for (int j = 0; j < 4; j++) L[idx * 4 + j] = f2bf(fv[j]);
        }
        __syncthreads();
        #pragma unroll 4
        for (int i = 0; i < 36; i++) {
            int ks = i * 2 + (tid >> 7);
            int r = (tid >> 5) & 3, c32 = tid & 31;
            int c = (ks & 7) * 32 + c32, k2 = ks >> 3;
            wt[(size_t)ks * 8192 + (o0 + r) * 32 + c32] = L[r * 2304 + c * 9 + k2];
        }
    }
}

// ---------------- fused sampler + GEMM, 2-deep software pipeline.
// Block: 512 thr = 8 waves, each wave 32(M) x 64(N). Grid: 512 flat, b = bx&7.
__global__ __launch_bounds__(512, 4)
void dcn_main(const float* __restrict__ off, const unsigned short* __restrict__ wt,
              const unsigned short* __restrict__ xt, float* __restrict__ out) {
    __shared__ __align__(16) unsigned short Sl[2][2][BN][SROW];  // 20480 B
    __shared__ __align__(16) int   tidx[NK2][BN][4];             // 9216 B (byte offs)
    __shared__ __align__(16) float twgt[NK2][BN][4];             // 9216 B

    const int b   = blockIdx.x & 7;
    const int p0  = (blockIdx.x >> 3) * BN;
    const int tid = threadIdx.x;
    const int lane = tid & 63;
    const int wv   = tid >> 6;
    const int quad = lane >> 4;
    const int l16  = lane & 15;
    const int moff = wv * 32;

    const int px  = tid >> 3;          // sampler: 8 threads/pixel
    const int sub = tid & 7;
    const int hh_ = sub >> 2;
    const int cc_ = (sub & 3) * 8;

    const char* xtb = (const char*)xt + (size_t)b * Pp * Cc * 2;

    // ---- taps for all 9 kernel points (b128 vector stores) ----
    for (int t = tid; t < NK2 * BN; t += 512) {
        int k2 = t >> 6, pxl = t & 63;
        int pl = p0 + pxl;
        int hh = pl >> 6, ww = pl & 63;
        int ky = k2 / 3, kx = k2 - ky * 3;
        float dy = off[((size_t)(b * 18 + 2 * k2    ) * Pp) + pl];
        float dx = off[((size_t)(b * 18 + 2 * k2 + 1) * Pp) + pl];
        float py  = (float)(hh - 1 + ky) + dy;
        float pxf = (float)(ww - 1 + kx) + dx;
        float y0f = floorf(py), x0f = floorf(pxf);
        int   y0 = (int)y0f,  x0 = (int)x0f;
        int   y1 = y0 + 1,    x1 = x0 + 1;
        float ly = py - y0f,  lx = pxf - x0f;
        float oy = 1.f - ly,  ox = 1.f - lx;
        bool vy0 = (y0 >= 0) && (y0 < Hh);
        bool vy1 = (y1 >= 0) && (y1 < Hh);
        bool vx0 = (x0 >= 0) && (x0 < Ww);
        bool vx1 = (x1 >= 0) && (x1 < Ww);
        int cy0 = imin(imax(y0, 0), Hh - 1), cy1 = imin(imax(y1, 0), Hh - 1);
        int cx0 = imin(imax(x0, 0), Ww - 1), cx1 = imin(imax(x1, 0), Ww - 1);
        i32x4 ti; f32x4 tw;
        ti[0] = (cy0 * Ww + cx0) * 512;  tw[0] = (vy0 && vx0) ? oy * ox : 0.f;
        ti[1] = (cy0 * Ww + cx1) * 512;  tw[1] = (vy0 && vx1) ? oy * lx : 0.f;
        ti[2] = (cy1 * Ww + cx0) * 512;  tw[2] = (vy1 && vx0) ? ly * ox : 0.f;
        ti[3] = (cy1 * Ww + cx1) * 512;  tw[3] = (vy1 && vx1) ? ly * lx : 0.f;
        *(i32x4*)&tidx[k2][pxl][0] = ti;
        *(f32x4*)&twgt[k2][pxl][0] = tw;
    }
    __syncthreads();

    // two gather chains (even pairs -> A, odd pairs -> B)
    int   tioA[4], tioB[4];
    float twA[4],  twB[4];
    uint4 gA[4],   gB[4];

    f32x4 acc[2][4];
    #pragma unroll
    for (int mt = 0; mt < 2; mt++)
        #pragma unroll
        for (int nt = 0; nt < 4; nt++) acc[mt][nt] = (f32x4){0.f, 0.f, 0.f, 0.f};

    // issue gathers for pair p into chain (g, tio, twv). Chain handles pairs
    // p, p+2, ...; k2 (=p>>2) changes on the chain exactly when (p&2)==0.
    auto issue = [&](int p, uint4 (&g)[4], int (&tio)[4], float (&twv)[4]) {
        if ((p & 2) == 0) {
            int k2 = p >> 2;
            i32x4 ti = *(const i32x4*)&tidx[k2][px][0];
            f32x4 tw = *(const f32x4*)&twgt[k2][px][0];
            #pragma unroll
            for (int t = 0; t < 4; t++) { tio[t] = ti[t]; twv[t] = tw[t]; }
        }
        const int coff = (p & 3) * 128 + sub * 16;
        #pragma unroll
        for (int t = 0; t < 4; t++)
            g[t] = *(const uint4*)(xtb + tio[t] + coff);
    };

    auto loadA = [&](int p, s16x8 (&dst)[2][2]) {
        const char* wb = (const char*)wt + ((size_t)p << 15);
        #pragma unroll
        for (int h = 0; h < 2; h++)
            #pragma unroll
            for (int mt = 0; mt < 2; mt++)
                dst[h][mt] = *(const s16x8*)(wb + h * 16384 +
                                             (moff + mt * 16 + l16) * 64 + quad * 16);
    };

    // reduce gathered taps -> pack bf16 -> store into Sl[prn&1]
    auto reduce_store = [&](int prn, uint4 (&g)[4], float (&twv)[4]) {
        float s0 = 0.f, s1 = 0.f, s2 = 0.f, s3 = 0.f, s4 = 0.f, s5 = 0.f, s6 = 0.f, s7 = 0.f;
        #pragma unroll
        for (int t = 0; t < 4; t++) {
            uint4 v = g[t];
            float wg = twv[t];
            s0 += wg * __uint_as_float(v.x << 16);
            s1 += wg * __uint_as_float(v.x);          // low bits = mantissa noise <2^-8
            s2 += wg * __uint_as_float(v.y << 16);
            s3 += wg * __uint_as_float(v.y);
            s4 += wg * __uint_as_float(v.z << 16);
            s5 += wg * __uint_as_float(v.z);
            s6 += wg * __uint_as_float(v.w << 16);
            s7 += wg * __uint_as_float(v.w);
        }
        uint4 d;
        d.x = __builtin_amdgcn_perm(__float_as_uint(s1), __float_as_uint(s0), 0x07060302u);
        d.y = __builtin_amdgcn_perm(__float_as_uint(s3), __float_as_uint(s2), 0x07060302u);
        d.z = __builtin_amdgcn_perm(__float_as_uint(s5), __float_as_uint(s4), 0x07060302u);
        d.w = __builtin_amdgcn_perm(__float_as_uint(s7), __float_as_uint(s6), 0x07060302u);
        *(uint4*)&Sl[prn & 1][hh_][px][cc_] = d;
    };

    s16x8 afA[2][2], afB[2][2];

    // one pipelined step: consume Sl[pr&1] with A-frags `cur`;
    // issue gathers for pr+2 (2-deep); prefetch A for pr+1; reduce pr+1's
    // gathers (issued one full step ago) into Sl[(pr+1)&1].
    auto step = [&](int pr, s16x8 (&cur)[2][2], s16x8 (&nxt)[2][2],
                    uint4 (&gIss)[4], int (&tioIss)[4], float (&twIss)[4],
                    uint4 (&gRed)[4], float (&twRed)[4]) {
        __syncthreads();                       // Sl[pr&1] now visible
        const int pi = pr + 2;
        if (pi < NPAIR) issue(pi, gIss, tioIss, twIss);
        const int pn = pr + 1;
        if (pn < NPAIR) loadA(pn, nxt);        // A-prefetch for pr+1
        // B fragments + MFMA on current buffer (overlaps the loads above;
        // MFMA's vmcnt wait on `cur` also drains gRed, which is older)
        s16x8 bfr[2][4];
        const char* sb = (const char*)&Sl[pr & 1][0][0][0];
        #pragma unroll
        for (int h = 0; h < 2; h++)
            #pragma unroll
            for (int nt = 0; nt < 4; nt++)
                bfr[h][nt] = *(const s16x8*)(sb + h * (BN * SROW * 2) +
                                             (nt * 16 + l16) * (SROW * 2) + quad * 16);
        #pragma unroll
        for (int h = 0; h < 2; h++)
            #pragma unroll
            for (int mt = 0; mt < 2; mt++)
                #pragma unroll
                for (int nt = 0; nt < 4; nt++)
                    acc[mt][nt] = __builtin_amdgcn_mfma_f32_16x16x32_bf16(
                        cur[h][mt], bfr[h][nt], acc[mt][nt], 0, 0, 0);
        if (pn < NPAIR) reduce_store(pn, gRed, twRed);
    };

    // preamble: gathers for pairs 0 (chain A) and 1 (chain B); A-frags for
    // pair 0; build Sl[0] from chain A.
    issue(0, gA, tioA, twA);
    issue(1, gB, tioB, twB);
    loadA(0, afA);
    reduce_store(0, gA, twA);

    for (int pr = 0; pr < NPAIR; pr += 2) {
        step(pr,     afA, afB, gA, tioA, twA, gB, twB);
        step(pr + 1, afB, afA, gB, tioB, twB, gA, twA);
    }

    // epilogue: C/D layout row(m)=quad*4+r, col(n)=l16
    float* op = out + ((size_t)b * Oo) * Pp + p0;
    #pragma unroll
    for (int mt = 0; mt < 2; mt++)
        #pragma unroll
        for (int nt = 0; nt < 4; nt++)
            #pragma unroll
            for (int r = 0; r < 4; r++) {
                int o_ = moff + mt * 16 + quad * 4 + r;
                int p_ = nt * 16 + l16;
                op[(size_t)o_ * Pp + p_] = acc[mt][nt][r];
            }
}

extern "C" void kernel_launch(void* const* d_in, const int* in_sizes, int n_in,
                              void* d_out, int out_size, void* d_ws, size_t ws_size,
                              hipStream_t stream) {
    (void)in_sizes; (void)n_in; (void)out_size; (void)ws_size;
    const float* x   = (const float*)d_in[0];
    const float* off = (const float*)d_in[1];
    const float* w   = (const float*)d_in[2];
    float* out = (float*)d_out;

    unsigned short* wt = (unsigned short*)d_ws;
    unsigned short* xt = (unsigned short*)((char*)d_ws + WT_BYTES);

    hipLaunchKernelGGL(prep, dim3(2112), dim3(256), 0, stream, x, w, xt, wt);
    hipLaunchKernelGGL(dcn_main, dim3(512), dim3(512), 0, stream, off, wt, xt, out);
}

// Round 4
// 176.925 us; speedup vs baseline: 1.6204x; 1.6204x over previous
//
#include <hip/hip_runtime.h>
#include <stdint.h>

// DCN v1 forward: B=8, C=256, H=W=64, K=3, pad=1, stride=1, O=256.
// Round 7. R3 post-mortem: 2-deep gather chains (+24 live regs) blew the
// 128-reg/thread budget -> scratch spill (WRITE_SIZE 0->546MB). R0 sits at
// the reg ceiling; occupancy is VGPR-pinned at 2 blocks/CU. New analysis:
// LDS pipe was ~84% busy (8 ds_read_b128/wave/step x 16 waves x 12cy =
// 63% + writes + 13% conflicts) and ALL 8 WAVES READ IDENTICAL B-frags
// (address independent of wv). Fix: wave tiling 8Mx1N -> 4Mx2N: each wave
// M=64 (4 mt) x N=32 (2 nt) -> B-reads/wave halve (8->4 b128), MFMA/wave
// unchanged, acc unchanged. A(wt)-traffic doubles but is L1/L2-resident.
// A-frags single-buffered af[2][4]; prefetch for pr+1 issued AFTER the
// MFMAs (WAR on af = prefetch w/o dbuf, no extra regs). Gathers back to
// proven 1-deep R0 schedule. Live regs ~105 < 128 -> no spill.

#define Bb 8
#define Cc 256
#define Hh 64
#define Ww 64
#define Pp 4096
#define Oo 256
#define NK2 9
#define NPAIR 36             // 36 pairs of K-steps (BK=64 each)
#define BN 64
#define SROW 40              // padded S row stride (elems)
#define WT_BYTES (2u * 72u * 256u * 32u)  // 1,179,648

typedef __attribute__((ext_vector_type(4))) float f32x4;
typedef __attribute__((ext_vector_type(8))) short s16x8;
typedef __attribute__((ext_vector_type(4))) int   i32x4;

static __device__ __forceinline__ unsigned short f2bf(float f) {
    union { float f; uint32_t u; } v; v.f = f;
    return (unsigned short)((v.u + 0x7fffu + ((v.u >> 16) & 1u)) >> 16);  // RNE
}
static __device__ __forceinline__ int imin(int a, int b) { return a < b ? a : b; }
static __device__ __forceinline__ int imax(int a, int b) { return a > b ? a : b; }

// ---------------- fused prep: x-transpose (blocks 0..2047) + weight (2048..2111)
// xT[b][p][c] bf16 ; wt[ks(72)][oc(256)][c32(32)] bf16, ks = k2*8+cch.
__global__ __launch_bounds__(256)
void prep(const float* __restrict__ x, const float* __restrict__ w,
          unsigned short* __restrict__ xt, unsigned short* __restrict__ wt) {
    __shared__ __align__(16) unsigned short L[9216];   // 18 KB, dual-purpose
    const int bx = blockIdx.x, tid = threadIdx.x;

    if (bx < 2048) {
        // ---- x: tile 64 c x 64 px ; b = bx&7 keeps XCD affinity with dcn_main
        unsigned short (*t2)[72] = (unsigned short(*)[72])L;  // 64 x 72 shorts
        const int b = bx & 7, ti = bx >> 3;
        const int c0 = (ti & 3) * 64, p0 = (ti >> 2) * 64;
        #pragma unroll
        for (int rd = 0; rd < 4; rd++) {
            int c = (tid >> 4) + rd * 16;
            int px4 = (tid & 15) * 4;
            f32x4 fv = *(const f32x4*)&x[(size_t)(b * Cc + c0 + c) * Pp + p0 + px4];
            #pragma unroll
            for (int j = 0; j < 4; j++) {
                int px = px4 + j;
                int chunk = ((c >> 3) + px) & 7;      // rotate chunks to spread banks
                t2[px][chunk * 8 + (c & 7)] = f2bf(fv[j]);
            }
        }
        __syncthreads();
        #pragma unroll
        for (int rd = 0; rd < 2; rd++) {
            int px = (tid >> 3) + rd * 32;
            int k = tid & 7;
            int chunk = (k + px) & 7;
            uint4 u = *(const uint4*)&t2[px][chunk * 8];
            *(uint4*)&xt[(size_t)(b * Pp + p0 + px) * Cc + c0 + k * 8] = u;
        }
    } else {
        // ---- weight: 64 blocks x 4 o-rows
        const int o0 = (bx - 2048) * 4;
        #pragma unroll
        for (int r9 = 0; r9 < 9; r9++) {
            int idx = r9 * 256 + tid;                  // 0..2303 float4s over 4 rows
            f32x4 fv = *(const f32x4*)&w[(size_t)o0 * 2304 + (size_t)idx * 4];
            #pragma unroll
            for (int j = 0; j < 4; j++) L[idx * 4 + j] = f2bf(fv[j]);
        }
        __syncthreads();
        #pragma unroll 4
        for (int i = 0; i < 36; i++) {
            int ks = i * 2 + (tid >> 7);
            int r = (tid >> 5) & 3, c32 = tid & 31;
            int c = (ks & 7) * 32 + c32, k2 = ks >> 3;
            wt[(size_t)ks * 8192 + (o0 + r) * 32 + c32] = L[r * 2304 + c * 9 + k2];
        }
    }
}

// ---------------- fused sampler + GEMM. 8 waves tiled 4(M) x 2(N):
// wave = 64 M-rows x 32 N-px -> B-frag LDS reads halved vs 8Mx1N.
// Grid: 512 flat, b = bx&7.
__global__ __launch_bounds__(512, 4)
void dcn_main(const float* __restrict__ off, const unsigned short* __restrict__ wt,
              const unsigned short* __restrict__ xt, float* __restrict__ out) {
    __shared__ __align__(16) unsigned short Sl[2][2][BN][SROW];  // 20480 B
    __shared__ __align__(16) int   tidx[NK2][BN][4];             // 9216 B (byte offs)
    __shared__ __align__(16) float twgt[NK2][BN][4];             // 9216 B

    const int b   = blockIdx.x & 7;
    const int p0  = (blockIdx.x >> 3) * BN;
    const int tid = threadIdx.x;
    const int lane = tid & 63;
    const int wv   = tid >> 6;
    const int quad = lane >> 4;
    const int l16  = lane & 15;
    const int wm   = wv & 3;           // M strip: 64 o-rows
    const int wn   = wv >> 2;          // N half: 32 px

    const int px  = tid >> 3;          // sampler: 8 threads/pixel
    const int sub = tid & 7;
    const int hh_ = sub >> 2;
    const int cc_ = (sub & 3) * 8;

    const char* xtb = (const char*)xt + (size_t)b * Pp * Cc * 2;

    // ---- taps for all 9 kernel points (b128 vector stores) ----
    for (int t = tid; t < NK2 * BN; t += 512) {
        int k2 = t >> 6, pxl = t & 63;
        int pl = p0 + pxl;
        int hh = pl >> 6, ww = pl & 63;
        int ky = k2 / 3, kx = k2 - ky * 3;
        float dy = off[((size_t)(b * 18 + 2 * k2    ) * Pp) + pl];
        float dx = off[((size_t)(b * 18 + 2 * k2 + 1) * Pp) + pl];
        float py  = (float)(hh - 1 + ky) + dy;
        float pxf = (float)(ww - 1 + kx) + dx;
        float y0f = floorf(py), x0f = floorf(pxf);
        int   y0 = (int)y0f,  x0 = (int)x0f;
        int   y1 = y0 + 1,    x1 = x0 + 1;
        float ly = py - y0f,  lx = pxf - x0f;
        float oy = 1.f - ly,  ox = 1.f - lx;
        bool vy0 = (y0 >= 0) && (y0 < Hh);
        bool vy1 = (y1 >= 0) && (y1 < Hh);
        bool vx0 = (x0 >= 0) && (x0 < Ww);
        bool vx1 = (x1 >= 0) && (x1 < Ww);
        int cy0 = imin(imax(y0, 0), Hh - 1), cy1 = imin(imax(y1, 0), Hh - 1);
        int cx0 = imin(imax(x0, 0), Ww - 1), cx1 = imin(imax(x1, 0), Ww - 1);
        i32x4 ti; f32x4 tw;
        ti[0] = (cy0 * Ww + cx0) * 512;  tw[0] = (vy0 && vx0) ? oy * ox : 0.f;
        ti[1] = (cy0 * Ww + cx1) * 512;  tw[1] = (vy0 && vx1) ? oy * lx : 0.f;
        ti[2] = (cy1 * Ww + cx0) * 512;  tw[2] = (vy1 && vx0) ? ly * ox : 0.f;
        ti[3] = (cy1 * Ww + cx1) * 512;  tw[3] = (vy1 && vx1) ? ly * lx : 0.f;
        *(i32x4*)&tidx[k2][pxl][0] = ti;
        *(f32x4*)&twgt[k2][pxl][0] = tw;
    }
    __syncthreads();

    int   tio[4];
    float twv[4];
    uint4 g[4];

    f32x4 acc[4][2];
    #pragma unroll
    for (int mt = 0; mt < 4; mt++)
        #pragma unroll
        for (int nt = 0; nt < 2; nt++) acc[mt][nt] = (f32x4){0.f, 0.f, 0.f, 0.f};

    // issue gathers for pair p (taps reload when p enters a new kernel point)
    auto issue = [&](int p) {
        if ((p & 3) == 0) {
            int k2 = p >> 2;
            i32x4 ti = *(const i32x4*)&tidx[k2][px][0];
            f32x4 tw = *(const f32x4*)&twgt[k2][px][0];
            #pragma unroll
            for (int t = 0; t < 4; t++) { tio[t] = ti[t]; twv[t] = tw[t]; }
        }
        const int coff = (p & 3) * 128 + sub * 16;
        #pragma unroll
        for (int t = 0; t < 4; t++)
            g[t] = *(const uint4*)(xtb + tio[t] + coff);
    };

    s16x8 af[2][4];
    auto loadA = [&](int p) {
        const char* wb = (const char*)wt + ((size_t)p << 15);
        #pragma unroll
        for (int h = 0; h < 2; h++)
            #pragma unroll
            for (int mt = 0; mt < 4; mt++)
                af[h][mt] = *(const s16x8*)(wb + h * 16384 +
                                            (wm * 64 + mt * 16 + l16) * 64 + quad * 16);
    };

    // reduce gathered taps -> pack bf16 -> store into Sl[prn&1]
    auto reduce_store = [&](int prn) {
        float s0 = 0.f, s1 = 0.f, s2 = 0.f, s3 = 0.f, s4 = 0.f, s5 = 0.f, s6 = 0.f, s7 = 0.f;
        #pragma unroll
        for (int t = 0; t < 4; t++) {
            uint4 v = g[t];
            float wg = twv[t];
            s0 += wg * __uint_as_float(v.x << 16);
            s1 += wg * __uint_as_float(v.x);          // low bits = mantissa noise <2^-8
            s2 += wg * __uint_as_float(v.y << 16);
            s3 += wg * __uint_as_float(v.y);
            s4 += wg * __uint_as_float(v.z << 16);
            s5 += wg * __uint_as_float(v.z);
            s6 += wg * __uint_as_float(v.w << 16);
            s7 += wg * __uint_as_float(v.w);
        }
        uint4 d;
        d.x = __builtin_amdgcn_perm(__float_as_uint(s1), __float_as_uint(s0), 0x07060302u);
        d.y = __builtin_amdgcn_perm(__float_as_uint(s3), __float_as_uint(s2), 0x07060302u);
        d.z = __builtin_amdgcn_perm(__float_as_uint(s5), __float_as_uint(s4), 0x07060302u);
        d.w = __builtin_amdgcn_perm(__float_as_uint(s7), __float_as_uint(s6), 0x07060302u);
        *(uint4*)&Sl[prn & 1][hh_][px][cc_] = d;
    };

    // preamble: gathers + A-frags for pair 0; build Sl[0]
    issue(0);
    loadA(0);
    reduce_store(0);

    for (int pr = 0; pr < NPAIR; ++pr) {
        __syncthreads();                   // Sl[pr&1] now visible
        const int pn = pr + 1;
        if (pn < NPAIR) issue(pn);         // gathers for next pair (oldest in queue)
        // B fragments (wave's own N half) + MFMA on current buffer
        s16x8 bfr[2][2];
        const char* sb = (const char*)&Sl[pr & 1][0][0][0];
        #pragma unroll
        for (int h = 0; h < 2; h++)
            #pragma unroll
            for (int nt = 0; nt < 2; nt++)
                bfr[h][nt] = *(const s16x8*)(sb + h * (BN * SROW * 2) +
                                             (wn * 32 + nt * 16 + l16) * (SROW * 2) + quad * 16);
        #pragma unroll
        for (int h = 0; h < 2; h++)
            #pragma unroll
            for (int mt = 0; mt < 4; mt++)
                #pragma unroll
                for (int nt = 0; nt < 2; nt++)
                    acc[mt][nt] = __builtin_amdgcn_mfma_f32_16x16x32_bf16(
                        af[h][mt], bfr[h][nt], acc[mt][nt], 0, 0, 0);
        if (pn < NPAIR) {
            loadA(pn);                     // af prefetch AFTER MFMAs: WAR reuse, no dbuf
            reduce_store(pn);              // waits on gathers only
        }
    }

    // epilogue: C/D layout row(m)=quad*4+r, col(n)=l16
    float* op = out + ((size_t)b * Oo) * Pp + p0;
    #pragma unroll
    for (int mt = 0; mt < 4; mt++)
        #pragma unroll
        for (int nt = 0; nt < 2; nt++)
            #pragma unroll
            for (int r = 0; r < 4; r++) {
                int o_ = wm * 64 + mt * 16 + quad * 4 + r;
                int p_ = wn * 32 + nt * 16 + l16;
                op[(size_t)o_ * Pp + p_] = acc[mt][nt][r];
            }
}

extern "C" void kernel_launch(void* const* d_in, const int* in_sizes, int n_in,
                              void* d_out, int out_size, void* d_ws, size_t ws_size,
                              hipStream_t stream) {
    (void)in_sizes; (void)n_in; (void)out_size; (void)ws_size;
    const float* x   = (const float*)d_in[0];
    const float* off = (const float*)d_in[1];
    const float* w   = (const float*)d_in[2];
    float* out = (float*)d_out;

    unsigned short* wt = (unsigned short*)d_ws;
    unsigned short* xt = (unsigned short*)((char*)d_ws + WT_BYTES);

    hipLaunchKernelGGL(prep, dim3(2112), dim3(256), 0, stream, x, w, xt, wt);
    hipLaunchKernelGGL(dcn_main, dim3(512), dim3(512), 0, stream, off, wt, xt, out);
}

// Round 5
// 158.242 us; speedup vs baseline: 1.8117x; 1.1181x over previous
//
#include <hip/hip_runtime.h>
#include <stdint.h>

// DCN v1 forward: B=8, C=256, H=W=64, K=3, pad=1, stride=1, O=256.
// Round 8. Evidence so far: R0 (73us) is latency/sync-bound: FETCH=15MB
// (gathers L2/L3-resident; b=bx&7 matches XCD round-robin so per-XCD set
// ~3.6MB < 4MB L2), MFMA true occupancy ~6%, LDS-read halving (R7) and
// split-K (R5) both regressed, +regs spills (128-reg ceiling @ 2 blk/CU).
// This round: keep R0's exact schedule + register set, but cut barriers
// 36->18 via ring-4 Sl (slot = pair&3, +20KB LDS -> 59KB, still 2 blk/CU).
// One superstep = one barrier + two pairs: at barrier, slots pr & pr+1 are
// both ready; we consume them while building pr+2, pr+3 into the other two
// slots. g single-buffer serial reuse (issue->reduce->issue->reduce), afA/afB
// dbuf restored (full-superstep A-load cover). Waves drift a full pair
// between barriers -> cross-wave stall cover without extra registers.

#define Bb 8
#define Cc 256
#define Hh 64
#define Ww 64
#define Pp 4096
#define Oo 256
#define NK2 9
#define NPAIR 36             // 36 pairs of K-steps (BK=64 each)
#define BN 64
#define SROW 40              // padded S row stride (elems)
#define WT_BYTES (2u * 72u * 256u * 32u)  // 1,179,648

typedef __attribute__((ext_vector_type(4))) float f32x4;
typedef __attribute__((ext_vector_type(8))) short s16x8;
typedef __attribute__((ext_vector_type(4))) int   i32x4;

static __device__ __forceinline__ unsigned short f2bf(float f) {
    union { float f; uint32_t u; } v; v.f = f;
    return (unsigned short)((v.u + 0x7fffu + ((v.u >> 16) & 1u)) >> 16);  // RNE
}
static __device__ __forceinline__ int imin(int a, int b) { return a < b ? a : b; }
static __device__ __forceinline__ int imax(int a, int b) { return a > b ? a : b; }

// ---------------- fused prep: x-transpose (blocks 0..2047) + weight (2048..2111)
// xT[b][p][c] bf16 ; wt[ks(72)][oc(256)][c32(32)] bf16, ks = k2*8+cch.
__global__ __launch_bounds__(256)
void prep(const float* __restrict__ x, const float* __restrict__ w,
          unsigned short* __restrict__ xt, unsigned short* __restrict__ wt) {
    __shared__ __align__(16) unsigned short L[9216];   // 18 KB, dual-purpose
    const int bx = blockIdx.x, tid = threadIdx.x;

    if (bx < 2048) {
        // ---- x: tile 64 c x 64 px ; b = bx&7 keeps XCD affinity with dcn_main
        unsigned short (*t2)[72] = (unsigned short(*)[72])L;  // 64 x 72 shorts
        const int b = bx & 7, ti = bx >> 3;
        const int c0 = (ti & 3) * 64, p0 = (ti >> 2) * 64;
        #pragma unroll
        for (int rd = 0; rd < 4; rd++) {
            int c = (tid >> 4) + rd * 16;
            int px4 = (tid & 15) * 4;
            f32x4 fv = *(const f32x4*)&x[(size_t)(b * Cc + c0 + c) * Pp + p0 + px4];
            #pragma unroll
            for (int j = 0; j < 4; j++) {
                int px = px4 + j;
                int chunk = ((c >> 3) + px) & 7;      // rotate chunks to spread banks
                t2[px][chunk * 8 + (c & 7)] = f2bf(fv[j]);
            }
        }
        __syncthreads();
        #pragma unroll
        for (int rd = 0; rd < 2; rd++) {
            int px = (tid >> 3) + rd * 32;
            int k = tid & 7;
            int chunk = (k + px) & 7;
            uint4 u = *(const uint4*)&t2[px][chunk * 8];
            *(uint4*)&xt[(size_t)(b * Pp + p0 + px) * Cc + c0 + k * 8] = u;
        }
    } else {
        // ---- weight: 64 blocks x 4 o-rows
        const int o0 = (bx - 2048) * 4;
        #pragma unroll
        for (int r9 = 0; r9 < 9; r9++) {
            int idx = r9 * 256 + tid;                  // 0..2303 float4s over 4 rows
            f32x4 fv = *(const f32x4*)&w[(size_t)o0 * 2304 + (size_t)idx * 4];
            #pragma unroll
            for (int j = 0; j < 4; j++) L[idx * 4 + j] = f2bf(fv[j]);
        }
        __syncthreads();
        #pragma unroll 4
        for (int i = 0; i < 36; i++) {
            int ks = i * 2 + (tid >> 7);
            int r = (tid >> 5) & 3, c32 = tid & 31;
            int c = (ks & 7) * 32 + c32, k2 = ks >> 3;
            wt[(size_t)ks * 8192 + (o0 + r) * 32 + c32] = L[r * 2304 + c * 9 + k2];
        }
    }
}

// ---------------- fused sampler + GEMM, ring-4 Sl, 1 barrier per 2 pairs.
// Block: 512 thr = 8 waves, each wave 32(M) x 64(N). Grid: 512 flat, b = bx&7.
__global__ __launch_bounds__(512, 4)
void dcn_main(const float* __restrict__ off, const unsigned short* __restrict__ wt,
              const unsigned short* __restrict__ xt, float* __restrict__ out) {
    __shared__ __align__(16) unsigned short Sl[4][2][BN][SROW];  // 40960 B ring-4
    __shared__ __align__(16) int   tidx[NK2][BN][4];             // 9216 B (byte offs)
    __shared__ __align__(16) float twgt[NK2][BN][4];             // 9216 B

    const int b   = blockIdx.x & 7;
    const int p0  = (blockIdx.x >> 3) * BN;
    const int tid = threadIdx.x;
    const int lane = tid & 63;
    const int wv   = tid >> 6;
    const int quad = lane >> 4;
    const int l16  = lane & 15;
    const int moff = wv * 32;

    const int px  = tid >> 3;          // sampler: 8 threads/pixel
    const int sub = tid & 7;
    const int hh_ = sub >> 2;
    const int cc_ = (sub & 3) * 8;

    const char* xtb = (const char*)xt + (size_t)b * Pp * Cc * 2;

    // ---- taps for all 9 kernel points (b128 vector stores) ----
    for (int t = tid; t < NK2 * BN; t += 512) {
        int k2 = t >> 6, pxl = t & 63;
        int pl = p0 + pxl;
        int hh = pl >> 6, ww = pl & 63;
        int ky = k2 / 3, kx = k2 - ky * 3;
        float dy = off[((size_t)(b * 18 + 2 * k2    ) * Pp) + pl];
        float dx = off[((size_t)(b * 18 + 2 * k2 + 1) * Pp) + pl];
        float py  = (float)(hh - 1 + ky) + dy;
        float pxf = (float)(ww - 1 + kx) + dx;
        float y0f = floorf(py), x0f = floorf(pxf);
        int   y0 = (int)y0f,  x0 = (int)x0f;
        int   y1 = y0 + 1,    x1 = x0 + 1;
        float ly = py - y0f,  lx = pxf - x0f;
        float oy = 1.f - ly,  ox = 1.f - lx;
        bool vy0 = (y0 >= 0) && (y0 < Hh);
        bool vy1 = (y1 >= 0) && (y1 < Hh);
        bool vx0 = (x0 >= 0) && (x0 < Ww);
        bool vx1 = (x1 >= 0) && (x1 < Ww);
        int cy0 = imin(imax(y0, 0), Hh - 1), cy1 = imin(imax(y1, 0), Hh - 1);
        int cx0 = imin(imax(x0, 0), Ww - 1), cx1 = imin(imax(x1, 0), Ww - 1);
        i32x4 ti; f32x4 tw;
        ti[0] = (cy0 * Ww + cx0) * 512;  tw[0] = (vy0 && vx0) ? oy * ox : 0.f;
        ti[1] = (cy0 * Ww + cx1) * 512;  tw[1] = (vy0 && vx1) ? oy * lx : 0.f;
        ti[2] = (cy1 * Ww + cx0) * 512;  tw[2] = (vy1 && vx0) ? ly * ox : 0.f;
        ti[3] = (cy1 * Ww + cx1) * 512;  tw[3] = (vy1 && vx1) ? ly * lx : 0.f;
        *(i32x4*)&tidx[k2][pxl][0] = ti;
        *(f32x4*)&twgt[k2][pxl][0] = tw;
    }
    __syncthreads();

    int   tio[4];
    float twv[4];
    uint4 g[4];

    f32x4 acc[2][4];
    #pragma unroll
    for (int mt = 0; mt < 2; mt++)
        #pragma unroll
        for (int nt = 0; nt < 4; nt++) acc[mt][nt] = (f32x4){0.f, 0.f, 0.f, 0.f};

    // issue gathers for pair p (taps reload when p enters a new kernel point)
    auto issue = [&](int p) {
        if ((p & 3) == 0) {
            int k2 = p >> 2;
            i32x4 ti = *(const i32x4*)&tidx[k2][px][0];
            f32x4 tw = *(const f32x4*)&twgt[k2][px][0];
            #pragma unroll
            for (int t = 0; t < 4; t++) { tio[t] = ti[t]; twv[t] = tw[t]; }
        }
        const int coff = (p & 3) * 128 + sub * 16;
        #pragma unroll
        for (int t = 0; t < 4; t++)
            g[t] = *(const uint4*)(xtb + tio[t] + coff);
    };

    auto loadA = [&](int p, s16x8 (&dst)[2][2]) {
        const char* wb = (const char*)wt + ((size_t)p << 15);
        #pragma unroll
        for (int h = 0; h < 2; h++)
            #pragma unroll
            for (int mt = 0; mt < 2; mt++)
                dst[h][mt] = *(const s16x8*)(wb + h * 16384 +
                                             (moff + mt * 16 + l16) * 64 + quad * 16);
    };

    // reduce gathered taps -> pack bf16 -> store into Sl[prn&3]
    auto reduce_store = [&](int prn) {
        float s0 = 0.f, s1 = 0.f, s2 = 0.f, s3 = 0.f, s4 = 0.f, s5 = 0.f, s6 = 0.f, s7 = 0.f;
        #pragma unroll
        for (int t = 0; t < 4; t++) {
            uint4 v = g[t];
            float wg = twv[t];
            s0 += wg * __uint_as_float(v.x << 16);
            s1 += wg * __uint_as_float(v.x);          // low bits = mantissa noise <2^-8
            s2 += wg * __uint_as_float(v.y << 16);
            s3 += wg * __uint_as_float(v.y);
            s4 += wg * __uint_as_float(v.z << 16);
            s5 += wg * __uint_as_float(v.z);
            s6 += wg * __uint_as_float(v.w << 16);
            s7 += wg * __uint_as_float(v.w);
        }
        uint4 d;
        d.x = __builtin_amdgcn_perm(__float_as_uint(s1), __float_as_uint(s0), 0x07060302u);
        d.y = __builtin_amdgcn_perm(__float_as_uint(s3), __float_as_uint(s2), 0x07060302u);
        d.z = __builtin_amdgcn_perm(__float_as_uint(s5), __float_as_uint(s4), 0x07060302u);
        d.w = __builtin_amdgcn_perm(__float_as_uint(s7), __float_as_uint(s6), 0x07060302u);
        *(uint4*)&Sl[prn & 3][hh_][px][cc_] = d;
    };

    // consume pair p with A-frags `af` (B-frags + 16 MFMA)
    auto mfma_pair = [&](int p, s16x8 (&af)[2][2]) {
        s16x8 bfr[2][4];
        const char* sb = (const char*)&Sl[p & 3][0][0][0];
        #pragma unroll
        for (int h = 0; h < 2; h++)
            #pragma unroll
            for (int nt = 0; nt < 4; nt++)
                bfr[h][nt] = *(const s16x8*)(sb + h * (BN * SROW * 2) +
                                             (nt * 16 + l16) * (SROW * 2) + quad * 16);
        #pragma unroll
        for (int h = 0; h < 2; h++)
            #pragma unroll
            for (int mt = 0; mt < 2; mt++)
                #pragma unroll
                for (int nt = 0; nt < 4; nt++)
                    acc[mt][nt] = __builtin_amdgcn_mfma_f32_16x16x32_bf16(
                        af[h][mt], bfr[h][nt], acc[mt][nt], 0, 0, 0);
    };

    s16x8 afA[2][2], afB[2][2];

    // preamble: build slots 0 and 1 (pairs 0,1); A-frags for pair 0.
    issue(0);
    loadA(0, afA);
    reduce_store(0);
    issue(1);
    reduce_store(1);

    // superstep loop: one barrier per 2 pairs. At barrier: slots pr, pr+1
    // ready; build pr+2, pr+3 into the opposite ring half.
    for (int pr = 0; pr < NPAIR; pr += 2) {
        __syncthreads();
        // -- half A: consume pair pr (afA), build pair pr+2
        if (pr + 2 < NPAIR) issue(pr + 2);          // gathers (oldest in queue)
        loadA(pr + 1, afB);                          // A dbuf: full-half cover
        mfma_pair(pr, afA);                          // covers gather latency
        if (pr + 2 < NPAIR) reduce_store(pr + 2);    // vmcnt waits gathers only
        // -- half B: consume pair pr+1 (afB), build pair pr+3
        if (pr + 3 < NPAIR) issue(pr + 3);
        if (pr + 2 < NPAIR) loadA(pr + 2, afA);
        mfma_pair(pr + 1, afB);
        if (pr + 3 < NPAIR) reduce_store(pr + 3);
    }

    // epilogue: C/D layout row(m)=quad*4+r, col(n)=l16
    float* op = out + ((size_t)b * Oo) * Pp + p0;
    #pragma unroll
    for (int mt = 0; mt < 2; mt++)
        #pragma unroll
        for (int nt = 0; nt < 4; nt++)
            #pragma unroll
            for (int r = 0; r < 4; r++) {
                int o_ = moff + mt * 16 + quad * 4 + r;
                int p_ = nt * 16 + l16;
                op[(size_t)o_ * Pp + p_] = acc[mt][nt][r];
            }
}

extern "C" void kernel_launch(void* const* d_in, const int* in_sizes, int n_in,
                              void* d_out, int out_size, void* d_ws, size_t ws_size,
                              hipStream_t stream) {
    (void)in_sizes; (void)n_in; (void)out_size; (void)ws_size;
    const float* x   = (const float*)d_in[0];
    const float* off = (const float*)d_in[1];
    const float* w   = (const float*)d_in[2];
    float* out = (float*)d_out;

    unsigned short* wt = (unsigned short*)d_ws;
    unsigned short* xt = (unsigned short*)((char*)d_ws + WT_BYTES);

    hipLaunchKernelGGL(prep, dim3(2112), dim3(256), 0, stream, x, w, xt, wt);
    hipLaunchKernelGGL(dcn_main, dim3(512), dim3(512), 0, stream, off, wt, xt, out);
}